// Round 15
// baseline (33.962 us; speedup 1.0000x reference)
//
#include <hip/hip_runtime.h>
#include <math.h>

#define B_N 4096
#define H_N 256
#define I_N 32
#define G3  768
#define NSEG 16                  // idx segments (16 blocks x 256 rows)
#define BKROW 4096               // bucket row stride (ints)

// ---- workspace layout (bytes) ----
#define WS_SC      0             // 16*32 ints = 2 KB (per-segment expert counts)
#define WS_BUCKET  2048          // 32*4096 ints = 512 KB
#define WS_B4      526336        // 32*256 float4 = 128 KB
#define WS_W5      657408        // 32*768*256 fp16 = 12.58 MB (fragment-major)
#define WS_NEEDED  13240320

typedef __attribute__((ext_vector_type(8))) _Float16 f16x8_t;
typedef __attribute__((ext_vector_type(4))) float f32x4_t;

__device__ __forceinline__ float sigm(float x) { return 1.0f / (1.0f + __expf(-x)); }
__device__ __forceinline__ float tanh_fast(float x) {
    float xc = fminf(fmaxf(x, -15.f), 15.f);
    float t = __expf(2.f * xc);
    return (t - 1.f) / (t + 1.f);
}

// --- fused aux: repack (768 blk) | bias4 (32 blk) | idx->bucket (16 blk) --
// (unchanged from R11/R14 — at its 38 MB BW floor)
__global__ __launch_bounds__(256) void k_aux(
    const float* __restrict__ w, unsigned short* __restrict__ w5,
    const float* __restrict__ b_ih, const float* __restrict__ b_hh,
    float4* __restrict__ b4,
    const float* __restrict__ inp, int* __restrict__ sc,
    int* __restrict__ bucket)
{
    int bid = blockIdx.x;
    int t = threadIdx.x;
    if (bid < 768) {
        // ---- repack: 8 g3-rows x 32 h x 32 e per block ----
        __shared__ float tl[8 * 1057];      // odd row stride: bank-spread
        int r0 = (bid >> 3) * 8;            // g3-row base (0..760)
        int ks = bid & 7;                   // h-tile = ks*32
#pragma unroll
        for (int it = 0; it < 8; ++it) {
            int f4 = it * 256 + t;          // 0..2047
            int e4 = (f4 & 7) * 4, hh = (f4 >> 3) & 31, r = f4 >> 8;
            float4 v = *(const float4*)(w + ((size_t)(r0 + r) * 256 + ks * 32 + hh) * 32 + e4);
            int bse = r * 1057 + hh * 33 + e4;
            tl[bse] = v.x; tl[bse + 1] = v.y; tl[bse + 2] = v.z; tl[bse + 3] = v.w;
        }
        __syncthreads();
        int rowgrp = r0 >> 4;
        int mbase = r0 & 15;                // 0 or 8
#pragma unroll
        for (int it = 0; it < 4; ++it) {
            int c = it * 256 + t;           // 0..1023
            int m8 = c & 7, kg = (c >> 3) & 3, e = c >> 5;
            union { _Float16 h[8]; uint4 v; } hi;
#pragma unroll
            for (int t8 = 0; t8 < 8; ++t8) {
                float f = tl[m8 * 1057 + (kg * 8 + t8) * 33 + e];
                hi.h[t8] = (_Float16)f;
            }
            size_t chunk = ((size_t)(e * 8 + ks) * 48 + rowgrp) * 64 + kg * 16 + mbase + m8;
            ((uint4*)w5)[chunk] = hi.v;
        }
    } else if (bid < 800) {
        // ---- bias4: b4[e][tt] = {r_sum, u_sum, n_ih, n_hh} ----
        int bb = bid - 768;
        int e = t & 31;
        int tt = bb * 8 + (t >> 5);
        float r = b_ih[tt * 32 + e] + b_hh[tt * 32 + e];
        float u = b_ih[(256 + tt) * 32 + e] + b_hh[(256 + tt) * 32 + e];
        float ni = b_ih[(512 + tt) * 32 + e];
        float nh = b_hh[(512 + tt) * 32 + e];
        float4 o = {r, u, ni, nh};
        b4[e * 256 + tt] = o;
    } else {
        // ---- one-hot -> expert index, segment-local bucket ----
        __shared__ int lhist[32];
        int seg = bid - 800;
        if (t < 32) lhist[t] = 0;
        __syncthreads();
        int b = seg * 256 + t;
        const float4* p = (const float4*)(inp + (size_t)b * I_N);
        int idx = 0;
#pragma unroll
        for (int k = 0; k < 8; ++k) {
            float4 v = p[k];
            if (v.x > 0.5f) idx = k * 4 + 0;
            if (v.y > 0.5f) idx = k * 4 + 1;
            if (v.z > 0.5f) idx = k * 4 + 2;
            if (v.w > 0.5f) idx = k * 4 + 3;
        }
        int lp = atomicAdd(&lhist[idx], 1);
        bucket[idx * BKROW + seg * 256 + lp] = b;
        __syncthreads();
        if (t < 32) sc[seg * 32 + t] = lhist[t];
    }
}

// --- swapped-operand MFMA GEMM: D = W * X.  NO LDS, NO BARRIERS. ----------
// 16x16x32 A/B fragment layouts are symmetric (lane&15 = row/col,
// lane>>4 = k-group), so the fragment-major w5 works unchanged as the
// A-operand.  B-operand (hx): lane loads its own 32 B k-slice of batch
// (lane&15) and converts fp32->fp16 in-register.  C (m89 layout):
// col = lane&15 = batch, row = (lane>>4)*4+reg = unit -> per-lane float4
// epilogue with fp32 x from global.  Waves fully independent.
__global__ __launch_bounds__(256, 4) void k_gemm_mfma(
    const unsigned short* __restrict__ w5,
    const float* __restrict__ hx, const float4* __restrict__ b4,
    const int* __restrict__ sc, const int* __restrict__ bucket,
    float* __restrict__ out)
{
    int bkt = blockIdx.x & 7, j0 = blockIdx.x >> 3;   // j0 in 0..33
    int t = threadIdx.x;

    // chunk counts for this bucket's 4 experts (uniform scalar math)
    int tot0 = 0, tot1 = 0, tot2 = 0, tot3 = 0;
#pragma unroll
    for (int j = 0; j < NSEG; ++j) {
        tot0 += sc[j * 32 + bkt];
        tot1 += sc[j * 32 + bkt + 8];
        tot2 += sc[j * 32 + bkt + 16];
        tot3 += sc[j * 32 + bkt + 24];
    }
    int c1 = (tot0 + 15) >> 4;
    int c2 = c1 + ((tot1 + 15) >> 4);
    int c3 = c2 + ((tot2 + 15) >> 4);
    int ntot = c3 + ((tot3 + 15) >> 4);

    int lane = t & 63, wv = t >> 6;
    int m = lane & 15, kg = lane >> 4;   // batch-within-chunk, k-group
    int q = blockIdx.y * 4 + wv;         // unit group 0..15

    for (int jj = j0; jj < ntot; jj += 34) {
        int ei = (jj < c1) ? 0 : (jj < c2) ? 1 : (jj < c3) ? 2 : 3;
        int ch = (jj < c1) ? jj : (jj < c2) ? jj - c1 : (jj < c3) ? jj - c2 : jj - c3;
        int te = (jj < c1) ? tot0 : (jj < c2) ? tot1 : (jj < c3) ? tot2 : tot3;
        int e = bkt + 8 * ei;
        int M = te - ch * 16; if (M > 16) M = 16;

        // W fragment base; issue ks=0 loads immediately
        const unsigned short* b_p = w5 + ((size_t)(e * 8) * 48 + q) * 512 + (size_t)lane * 8;
        f16x8_t wc0 = *(const f16x8_t*)(b_p);
        f16x8_t wc1 = *(const f16x8_t*)(b_p + (size_t)16 * 512);
        f16x8_t wc2 = *(const f16x8_t*)(b_p + (size_t)32 * 512);

        // resolve this lane's batch id (lane&15) via segment scan
        int b = -1;
        {
            int rank = ch * 16 + m;
            if (m < M) {
                int acc = 0, seg = 0, off = 0;
#pragma unroll
                for (int j = 0; j < NSEG; ++j) {
                    int c = sc[j * 32 + e];
                    if (rank >= acc && rank < acc + c) { seg = j; off = rank - acc; }
                    acc += c;
                }
                b = bucket[e * BKROW + seg * 256 + off];
            }
        }
        int bidc = (b >= 0) ? b : 0;     // clamp: garbage cols skipped at write
        const float* xsrc = hx + ((size_t)bidc << 8) + kg * 8;

        // X slice ks=0 (32 B per lane)
        float4 xa = *(const float4*)(xsrc);
        float4 xb = *(const float4*)(xsrc + 4);

        f32x4_t ac0 = {0.f, 0.f, 0.f, 0.f};
        f32x4_t ac1 = {0.f, 0.f, 0.f, 0.f};
        f32x4_t ac2 = {0.f, 0.f, 0.f, 0.f};

        // K-loop: depth-2 pipeline on W and X, no barriers
#pragma unroll
        for (int ks = 0; ks < 8; ++ks) {
            f16x8_t wn0 = wc0, wn1 = wc1, wn2 = wc2;
            float4 xna = xa, xnb = xb;
            if (ks < 7) {
                const unsigned short* np = b_p + (size_t)(ks + 1) * 48 * 512;
                wn0 = *(const f16x8_t*)(np);
                wn1 = *(const f16x8_t*)(np + (size_t)16 * 512);
                wn2 = *(const f16x8_t*)(np + (size_t)32 * 512);
                xna = *(const float4*)(xsrc + (ks + 1) * 32);
                xnb = *(const float4*)(xsrc + (ks + 1) * 32 + 4);
            }
            f16x8_t xf = { (_Float16)xa.x, (_Float16)xa.y, (_Float16)xa.z,
                           (_Float16)xa.w, (_Float16)xb.x, (_Float16)xb.y,
                           (_Float16)xb.z, (_Float16)xb.w };
            ac0 = __builtin_amdgcn_mfma_f32_16x16x32_f16(wc0, xf, ac0, 0, 0, 0);
            ac1 = __builtin_amdgcn_mfma_f32_16x16x32_f16(wc1, xf, ac1, 0, 0, 0);
            ac2 = __builtin_amdgcn_mfma_f32_16x16x32_f16(wc2, xf, ac2, 0, 0, 0);
            wc0 = wn0; wc1 = wn1; wc2 = wn2;
            xa = xna; xb = xnb;
        }

        // epilogue: lane owns batch b (col) x 4 units (rows kg*4+i)
        if (b >= 0) {
            int u0 = q * 16 + kg * 4;
            float4 xv = *(const float4*)(hx + ((size_t)b << 8) + u0);
            float xr[4] = {xv.x, xv.y, xv.z, xv.w};
            float orr[4];
#pragma unroll
            for (int i = 0; i < 4; ++i) {
                float4 bs = b4[e * 256 + u0 + i];
                float r = sigm(ac0[i] + bs.x);
                float u = sigm(ac1[i] + bs.y);
                float n = tanh_fast(bs.z + r * (ac2[i] + bs.w));
                orr[i] = u * xr[i] + (1.0f - u) * n;
            }
            float4 ov = {orr[0], orr[1], orr[2], orr[3]};
            *(float4*)(out + ((size_t)b << 8) + u0) = ov;
        }
    }
}

// --- fallback: correct but slow, if ws too small --------------------------
__global__ void k_naive(const float* __restrict__ inp, const float* __restrict__ hx,
                        const float* __restrict__ w, const float* __restrict__ b_ih,
                        const float* __restrict__ b_hh, float* __restrict__ out) {
    int b = blockIdx.x;
    int t = threadIdx.x;
    __shared__ float sx[H_N];
    __shared__ int sidx;
    if (t == 0) {
        int idx = 0;
        for (int i = 0; i < I_N; ++i)
            if (inp[b * I_N + i] > 0.5f) idx = i;
        sidx = idx;
    }
    sx[t] = hx[b * H_N + t];
    __syncthreads();
    int i = sidx;
    float a0 = 0.f, a1 = 0.f, a2 = 0.f;
    for (int h = 0; h < H_N; ++h) {
        float xv = sx[h];
        a0 = fmaf(w[(t * H_N + h) * I_N + i], xv, a0);
        a1 = fmaf(w[((256 + t) * H_N + h) * I_N + i], xv, a1);
        a2 = fmaf(w[((512 + t) * H_N + h) * I_N + i], xv, a2);
    }
    float r = sigm(b_ih[t * I_N + i] + a0 + b_hh[t * I_N + i]);
    float u = sigm(b_ih[(256 + t) * I_N + i] + a1 + b_hh[(256 + t) * I_N + i]);
    float n = tanhf(b_ih[(512 + t) * I_N + i] + r * (a2 + b_hh[(512 + t) * I_N + i]));
    out[b * H_N + t] = u * sx[t] + (1.0f - u) * n;
}

extern "C" void kernel_launch(void* const* d_in, const int* in_sizes, int n_in,
                              void* d_out, int out_size, void* d_ws, size_t ws_size,
                              hipStream_t stream) {
    const float* inp  = (const float*)d_in[0];
    const float* hx   = (const float*)d_in[1];
    const float* w    = (const float*)d_in[2];
    const float* b_ih = (const float*)d_in[3];
    const float* b_hh = (const float*)d_in[4];
    float* out = (float*)d_out;

    if (ws_size < (size_t)WS_NEEDED) {
        k_naive<<<B_N, H_N, 0, stream>>>(inp, hx, w, b_ih, b_hh, out);
        return;
    }

    char* ws = (char*)d_ws;
    int* sc     = (int*)(ws + WS_SC);
    int* bucket = (int*)(ws + WS_BUCKET);
    float4* b4  = (float4*)(ws + WS_B4);
    unsigned short* w5 = (unsigned short*)(ws + WS_W5);

    k_aux<<<816, 256, 0, stream>>>(w, w5, b_ih, b_hh, b4, inp, sc, bucket);
    k_gemm_mfma<<<dim3(272, 4), 256, 0, stream>>>(w5, hx, b4, sc, bucket, out);
}

// Round 16
// 26.883 us; speedup vs baseline: 1.2633x; 1.2633x over previous
//
#include <hip/hip_runtime.h>
#include <math.h>

#define B_N 4096
#define H_N 256
#define I_N 32
#define G3  768
#define NSEG 16                  // idx segments (16 blocks x 256 rows)
#define BKROW 4096               // bucket row stride (ints)

// ---- workspace layout (bytes) ----
#define WS_SC      0             // 16*32 ints = 2 KB (per-segment expert counts)
#define WS_BUCKET  2048          // 32*4096 ints = 512 KB
#define WS_B4      526336        // 32*256 float4 = 128 KB
#define WS_W5      657408        // 32*768*256 fp16 = 12.58 MB (fragment-major)
#define WS_NEEDED  13240320

typedef __attribute__((ext_vector_type(8))) _Float16 f16x8_t;
typedef __attribute__((ext_vector_type(4))) float f32x4_t;

__device__ __forceinline__ float sigm(float x) { return 1.0f / (1.0f + __expf(-x)); }
__device__ __forceinline__ float tanh_fast(float x) {
    float xc = fminf(fmaxf(x, -15.f), 15.f);
    float t = __expf(2.f * xc);
    return (t - 1.f) / (t + 1.f);
}

// --- fused aux: repack (768 blk) | bias4 (32 blk) | idx->bucket (16 blk) --
// repack: w[g3][h][e] fp32 -> fragment-major SINGLE fp16:
//   w5[(e*8+ks)*48 + rowgrp][lane] as uint4; lane = kg*16+m16 holds
//   row = rowgrp*16+m16, k = ks*32+kg*8+0..7.  Each MFMA B-fragment is a
//   contiguous 1 KB block read as lane-consecutive dwordx4 (no gather).
// idx: segment seg owns rows [seg*256,+256); block-local LDS ranks ->
//   bucket[e][seg*256+lp]; counts -> sc[seg][e]. No global atomics/memset.
__global__ __launch_bounds__(256) void k_aux(
    const float* __restrict__ w, unsigned short* __restrict__ w5,
    const float* __restrict__ b_ih, const float* __restrict__ b_hh,
    float4* __restrict__ b4,
    const float* __restrict__ inp, int* __restrict__ sc,
    int* __restrict__ bucket)
{
    int bid = blockIdx.x;
    int t = threadIdx.x;
    if (bid < 768) {
        // ---- repack: 8 g3-rows x 32 h x 32 e per block ----
        __shared__ float tl[8 * 1057];      // odd row stride: bank-spread
        int r0 = (bid >> 3) * 8;            // g3-row base (0..760)
        int ks = bid & 7;                   // h-tile = ks*32
#pragma unroll
        for (int it = 0; it < 8; ++it) {
            int f4 = it * 256 + t;          // 0..2047
            int e4 = (f4 & 7) * 4, hh = (f4 >> 3) & 31, r = f4 >> 8;
            float4 v = *(const float4*)(w + ((size_t)(r0 + r) * 256 + ks * 32 + hh) * 32 + e4);
            int bse = r * 1057 + hh * 33 + e4;
            tl[bse] = v.x; tl[bse + 1] = v.y; tl[bse + 2] = v.z; tl[bse + 3] = v.w;
        }
        __syncthreads();
        int rowgrp = r0 >> 4;
        int mbase = r0 & 15;                // 0 or 8
#pragma unroll
        for (int it = 0; it < 4; ++it) {
            int c = it * 256 + t;           // 0..1023
            int m8 = c & 7, kg = (c >> 3) & 3, e = c >> 5;
            union { _Float16 h[8]; uint4 v; } hi;
#pragma unroll
            for (int t8 = 0; t8 < 8; ++t8) {
                float f = tl[m8 * 1057 + (kg * 8 + t8) * 33 + e];
                hi.h[t8] = (_Float16)f;
            }
            size_t chunk = ((size_t)(e * 8 + ks) * 48 + rowgrp) * 64 + kg * 16 + mbase + m8;
            ((uint4*)w5)[chunk] = hi.v;
        }
    } else if (bid < 800) {
        // ---- bias4: b4[e][tt] = {r_sum, u_sum, n_ih, n_hh} ----
        int bb = bid - 768;
        int e = t & 31;
        int tt = bb * 8 + (t >> 5);
        float r = b_ih[tt * 32 + e] + b_hh[tt * 32 + e];
        float u = b_ih[(256 + tt) * 32 + e] + b_hh[(256 + tt) * 32 + e];
        float ni = b_ih[(512 + tt) * 32 + e];
        float nh = b_hh[(512 + tt) * 32 + e];
        float4 o = {r, u, ni, nh};
        b4[e * 256 + tt] = o;
    } else {
        // ---- one-hot -> expert index, segment-local bucket ----
        __shared__ int lhist[32];
        int seg = bid - 800;
        if (t < 32) lhist[t] = 0;
        __syncthreads();
        int b = seg * 256 + t;
        const float4* p = (const float4*)(inp + (size_t)b * I_N);
        int idx = 0;
#pragma unroll
        for (int k = 0; k < 8; ++k) {
            float4 v = p[k];
            if (v.x > 0.5f) idx = k * 4 + 0;
            if (v.y > 0.5f) idx = k * 4 + 1;
            if (v.z > 0.5f) idx = k * 4 + 2;
            if (v.w > 0.5f) idx = k * 4 + 3;
        }
        int lp = atomicAdd(&lhist[idx], 1);
        bucket[idx * BKROW + seg * 256 + lp] = b;
        __syncthreads();
        if (t < 32) sc[seg * 32 + t] = lhist[t];
    }
}

// --- grouped MFMA GEMM + inline plan + fused GRU epilogue, M=16 -----------
// bucket bkt = blockIdx.x&7 owns experts {bkt,+8,+16,+24} (XCD-affine:
// 272%8==0, grid-y preserves phase). j-slots grid-stride for skew. B
// fragments software-pipelined (depth 2, first loads issued before the
// A-stage barrier). Epilogue x read back from LDS A (fp16-rounded hx).
__global__ __launch_bounds__(256, 4) void k_gemm_mfma(
    const unsigned short* __restrict__ w5,
    const float* __restrict__ hx, const float4* __restrict__ b4,
    const int* __restrict__ sc, const int* __restrict__ bucket,
    float* __restrict__ out)
{
    int bkt = blockIdx.x & 7, j0 = blockIdx.x >> 3;   // j0 in 0..33
    int t = threadIdx.x;

    // chunk counts for this bucket's 4 experts (all uniform scalar math)
    int tot0 = 0, tot1 = 0, tot2 = 0, tot3 = 0;
#pragma unroll
    for (int j = 0; j < NSEG; ++j) {
        tot0 += sc[j * 32 + bkt];
        tot1 += sc[j * 32 + bkt + 8];
        tot2 += sc[j * 32 + bkt + 16];
        tot3 += sc[j * 32 + bkt + 24];
    }
    int c1 = (tot0 + 15) >> 4;
    int c2 = c1 + ((tot1 + 15) >> 4);
    int c3 = c2 + ((tot2 + 15) >> 4);
    int ntot = c3 + ((tot3 + 15) >> 4);

    __shared__ _Float16 Ah[16 * 256];   // 8 KB
    __shared__ int bids[16];

    int lane = t & 63, wv = t >> 6;
    int m16 = lane & 15, kg = lane >> 4;
    int q = blockIdx.y * 4 + wv;         // unit group 0..15

    for (int jj = j0; jj < ntot; jj += 34) {
        int ei = (jj < c1) ? 0 : (jj < c2) ? 1 : (jj < c3) ? 2 : 3;
        int ch = (jj < c1) ? jj : (jj < c2) ? jj - c1 : (jj < c3) ? jj - c2 : jj - c3;
        int te = (jj < c1) ? tot0 : (jj < c2) ? tot1 : (jj < c3) ? tot2 : tot3;
        int e = bkt + 8 * ei;
        int M = te - ch * 16; if (M > 16) M = 16;

        // fragment base; issue ks=0 loads NOW (hide under A-stage + barrier)
        const unsigned short* b_p = w5 + ((size_t)(e * 8) * 48 + q) * 512 + (size_t)lane * 8;
        f16x8_t bc0 = *(const f16x8_t*)(b_p);
        f16x8_t bc1 = *(const f16x8_t*)(b_p + (size_t)16 * 512);
        f16x8_t bc2 = *(const f16x8_t*)(b_p + (size_t)32 * 512);

        // resolve batch id via segment scan (sc reads are uniform/scalar)
        int row = t >> 4, c16 = t & 15;
        int b = -1;
        if (row < M) {
            int rank = ch * 16 + row;
            int acc = 0, seg = 0, off = 0;
#pragma unroll
            for (int j = 0; j < NSEG; ++j) {
                int c = sc[j * 32 + e];
                if (rank >= acc && rank < acc + c) { seg = j; off = rank - acc; }
                acc += c;
            }
            b = bucket[e * BKROW + seg * 256 + off];
        }
        if (c16 == 0) bids[row] = b;

        // stage A: row (batch), c16 owns k in [c16*16, +16), fp32 -> fp16
        if (b >= 0) {
            const float* src = hx + ((size_t)b << 8) + c16 * 16;
            float fv[16];
#pragma unroll
            for (int p = 0; p < 4; ++p)
                *(float4*)&fv[p * 4] = *(const float4*)(src + p * 4);
#pragma unroll
            for (int p = 0; p < 2; ++p) {
                union { _Float16 h[8]; uint4 v; } hu;
#pragma unroll
                for (int jj2 = 0; jj2 < 8; ++jj2)
                    hu.h[jj2] = (_Float16)fv[p * 8 + jj2];
                int col = (c16 * 2 + p) ^ (row & 7);
                *(uint4*)&Ah[row * 256 + col * 8] = hu.v;
            }
        } else {
            uint4 z = {0, 0, 0, 0};
#pragma unroll
            for (int p = 0; p < 2; ++p) {
                int col = (c16 * 2 + p) ^ (row & 7);
                *(uint4*)&Ah[row * 256 + col * 8] = z;
            }
        }
        __syncthreads();

        f32x4_t ac0 = {0.f, 0.f, 0.f, 0.f};
        f32x4_t ac1 = {0.f, 0.f, 0.f, 0.f};
        f32x4_t ac2 = {0.f, 0.f, 0.f, 0.f};

        // K-loop: depth-2 pipeline (load ks+1 while MFMAing ks)
#pragma unroll
        for (int ks = 0; ks < 8; ++ks) {
            f16x8_t bn0 = bc0, bn1 = bc1, bn2 = bc2;
            if (ks < 7) {
                const unsigned short* np = b_p + (size_t)(ks + 1) * 48 * 512;
                bn0 = *(const f16x8_t*)(np);
                bn1 = *(const f16x8_t*)(np + (size_t)16 * 512);
                bn2 = *(const f16x8_t*)(np + (size_t)32 * 512);
            }
            int sw = ((ks * 4 + kg) ^ (m16 & 7)) << 3;
            f16x8_t a0 = *(const f16x8_t*)&Ah[m16 * 256 + sw];
            ac0 = __builtin_amdgcn_mfma_f32_16x16x32_f16(a0, bc0, ac0, 0, 0, 0);
            ac1 = __builtin_amdgcn_mfma_f32_16x16x32_f16(a0, bc1, ac1, 0, 0, 0);
            ac2 = __builtin_amdgcn_mfma_f32_16x16x32_f16(a0, bc2, ac2, 0, 0, 0);
            bc0 = bn0; bc1 = bn1; bc2 = bn2;
        }

        // fused GRU epilogue: C row=(lane>>4)*4+i (batch), col=lane&15 (unit)
        int mg = (lane >> 4) * 4;
        int tt = q * 16 + m16;
        float4 bs = b4[e * 256 + tt];
#pragma unroll
        for (int i = 0; i < 4; ++i) {
            int mr = mg + i;
            if (mr < M) {
                int bb = bids[mr];
                // x = staged fp16(hx[bb][tt]) from LDS (k-space == unit-space)
                int xc = ((tt >> 3) ^ (mr & 7)) * 8 + (tt & 7);
                float x = (float)Ah[mr * 256 + xc];
                float r = sigm(ac0[i] + bs.x);
                float u = sigm(ac1[i] + bs.y);
                float n = tanh_fast(bs.z + r * (ac2[i] + bs.w));
                out[(size_t)bb * 256 + tt] = u * x + (1.0f - u) * n;
            }
        }
        __syncthreads();   // protect Ah/bids before next chunk restage
    }
}

// --- fallback: correct but slow, if ws too small --------------------------
__global__ void k_naive(const float* __restrict__ inp, const float* __restrict__ hx,
                        const float* __restrict__ w, const float* __restrict__ b_ih,
                        const float* __restrict__ b_hh, float* __restrict__ out) {
    int b = blockIdx.x;
    int t = threadIdx.x;
    __shared__ float sx[H_N];
    __shared__ int sidx;
    if (t == 0) {
        int idx = 0;
        for (int i = 0; i < I_N; ++i)
            if (inp[b * I_N + i] > 0.5f) idx = i;
        sidx = idx;
    }
    sx[t] = hx[b * H_N + t];
    __syncthreads();
    int i = sidx;
    float a0 = 0.f, a1 = 0.f, a2 = 0.f;
    for (int h = 0; h < H_N; ++h) {
        float xv = sx[h];
        a0 = fmaf(w[(t * H_N + h) * I_N + i], xv, a0);
        a1 = fmaf(w[((256 + t) * H_N + h) * I_N + i], xv, a1);
        a2 = fmaf(w[((512 + t) * H_N + h) * I_N + i], xv, a2);
    }
    float r = sigm(b_ih[t * I_N + i] + a0 + b_hh[t * I_N + i]);
    float u = sigm(b_ih[(256 + t) * I_N + i] + a1 + b_hh[(256 + t) * I_N + i]);
    float n = tanhf(b_ih[(512 + t) * I_N + i] + r * (a2 + b_hh[(512 + t) * I_N + i]));
    out[b * H_N + t] = u * sx[t] + (1.0f - u) * n;
}

extern "C" void kernel_launch(void* const* d_in, const int* in_sizes, int n_in,
                              void* d_out, int out_size, void* d_ws, size_t ws_size,
                              hipStream_t stream) {
    const float* inp  = (const float*)d_in[0];
    const float* hx   = (const float*)d_in[1];
    const float* w    = (const float*)d_in[2];
    const float* b_ih = (const float*)d_in[3];
    const float* b_hh = (const float*)d_in[4];
    float* out = (float*)d_out;

    if (ws_size < (size_t)WS_NEEDED) {
        k_naive<<<B_N, H_N, 0, stream>>>(inp, hx, w, b_ih, b_hh, out);
        return;
    }

    char* ws = (char*)d_ws;
    int* sc     = (int*)(ws + WS_SC);
    int* bucket = (int*)(ws + WS_BUCKET);
    float4* b4  = (float4*)(ws + WS_B4);
    unsigned short* w5 = (unsigned short*)(ws + WS_W5);

    k_aux<<<816, 256, 0, stream>>>(w, w5, b_ih, b_hh, b4, inp, sc, bucket);
    k_gemm_mfma<<<dim3(272, 4), 256, 0, stream>>>(w5, hx, b4, sc, bucket, out);
}